// Round 3
// baseline (3305.170 us; speedup 1.0000x reference)
//
#include <hip/hip_runtime.h>
#include <math.h>

// ---------------- problem constants ----------------
#define B_ 8192
#define IN_ 512
#define NQ 16
#define DD 128
#define OO 256
#define PI_F 3.14159274101257324f
#define INV_B (1.0f/8192.0f)
#define SCALE_F 0.176776695296636881f   // 1/sqrt(32)

// ---------------- d_out offsets (floats) ----------------
#define OFF_CLASS 0
#define OFF_PROBS 2097152
#define OFF_ATTRM 2228224
#define OFF_ATTIM 3276800
#define OFF_PUR   4325376
#define OFF_ENT   4325377
#define OFF_FID   4325378
#define OFF_PV    6422530

// =====================================================================
// K0: Cayley transform  U = (I - iA)^-1 (I + iA), A = A_param - A_param^T
// =====================================================================
__global__ __launch_bounds__(256) void cayley_kernel(const float* __restrict__ A_param,
                                                     float* __restrict__ Ur,
                                                     float* __restrict__ Ui) {
    __shared__ float Mr[16][17], Mi[16][17], Rr[16][17], Ri[16][17];
    const int t = threadIdx.x;
    const int r = t >> 4, c = t & 15;
    float a = A_param[r*16 + c] - A_param[c*16 + r];
    Mr[r][c] = (r == c) ? 1.0f : 0.0f;
    Mi[r][c] = -a;
    Rr[r][c] = (r == c) ? 1.0f : 0.0f;
    Ri[r][c] = a;
    __syncthreads();
    for (int p = 0; p < 16; p++) {
        float prr = Mr[p][p], pii = Mi[p][p];
        __syncthreads();
        if (r == p) {
            float inv = 1.0f / (prr*prr + pii*pii);
            float mr0 = Mr[p][c], mi0 = Mi[p][c];
            Mr[p][c] = (mr0*prr + mi0*pii) * inv;
            Mi[p][c] = (mi0*prr - mr0*pii) * inv;
            float rr0 = Rr[p][c], ri0 = Ri[p][c];
            Rr[p][c] = (rr0*prr + ri0*pii) * inv;
            Ri[p][c] = (ri0*prr - rr0*pii) * inv;
        }
        __syncthreads();
        float fr = Mr[r][p], fi = Mi[r][p];
        float mpr = Mr[p][c], mpi = Mi[p][c];
        float rpr = Rr[p][c], rpi = Ri[p][c];
        __syncthreads();
        if (r != p) {
            Mr[r][c] -= fr*mpr - fi*mpi;
            Mi[r][c] -= fr*mpi + fi*mpr;
            Rr[r][c] -= fr*rpr - fi*rpi;
            Ri[r][c] -= fr*rpi + fi*rpr;
        }
        __syncthreads();
    }
    Ur[t] = Rr[r][c];
    Ui[t] = Ri[r][c];
}

// =====================================================================
// Generic fp32 GEMM: C[M x N] = A[M x K] @ W[K x N] + bias  (128x128x32)
// =====================================================================
__global__ __launch_bounds__(256) void gemm_f32(const float* __restrict__ A, int lda,
                                                const float* __restrict__ W, int ldw,
                                                const float* __restrict__ bias,
                                                float* __restrict__ C, int ldc, int K) {
    __shared__ float As[32][132];
    __shared__ float Bs[32][132];
    const int t = threadIdx.x;
    const int tm = t >> 4, tn = t & 15;
    const size_t r0 = (size_t)blockIdx.x * 128;
    const int c0 = blockIdx.y * 128;
    float acc[8][8];
#pragma unroll
    for (int i = 0; i < 8; i++)
#pragma unroll
        for (int j = 0; j < 8; j++) acc[i][j] = 0.0f;

    for (int k0 = 0; k0 < K; k0 += 32) {
#pragma unroll
        for (int i = 0; i < 4; i++) {
            int idx = t + i*256;
            int mm = idx >> 3, kq = (idx & 7) << 2;
            float4 va = *(const float4*)&A[(r0 + mm)*lda + (k0 + kq)];
            As[kq+0][mm] = va.x; As[kq+1][mm] = va.y;
            As[kq+2][mm] = va.z; As[kq+3][mm] = va.w;
        }
#pragma unroll
        for (int i = 0; i < 4; i++) {
            int idx = t + i*256;
            int kk = idx >> 5, cq = (idx & 31) << 2;
            *(float4*)&Bs[kk][cq] = *(const float4*)&W[(size_t)(k0+kk)*ldw + (c0+cq)];
        }
        __syncthreads();
#pragma unroll
        for (int kk = 0; kk < 32; kk++) {
            float4 a0 = *(const float4*)&As[kk][tm*4];
            float4 a1 = *(const float4*)&As[kk][64 + tm*4];
            float4 b0 = *(const float4*)&Bs[kk][tn*4];
            float4 b1 = *(const float4*)&Bs[kk][64 + tn*4];
            float av[8] = {a0.x,a0.y,a0.z,a0.w,a1.x,a1.y,a1.z,a1.w};
            float bv[8] = {b0.x,b0.y,b0.z,b0.w,b1.x,b1.y,b1.z,b1.w};
#pragma unroll
            for (int i = 0; i < 8; i++)
#pragma unroll
                for (int j = 0; j < 8; j++)
                    acc[i][j] = fmaf(av[i], bv[j], acc[i][j]);
        }
        __syncthreads();
    }
#pragma unroll
    for (int ri = 0; ri < 2; ri++)
#pragma unroll
    for (int i = 0; i < 4; i++) {
        size_t row = r0 + ri*64 + tm*4 + i;
#pragma unroll
        for (int ci = 0; ci < 2; ci++) {
            int col = c0 + ci*64 + tn*4;
            float4 bb = *(const float4*)&bias[col];
            float4 v;
            v.x = acc[ri*4+i][ci*4+0] + bb.x;
            v.y = acc[ri*4+i][ci*4+1] + bb.y;
            v.z = acc[ri*4+i][ci*4+2] + bb.z;
            v.w = acc[ri*4+i][ci*4+3] + bb.w;
            *(float4*)&C[row*ldc + col] = v;
        }
    }
}

// =====================================================================
// K1b: phases[b,n] = tanh(x[b]·W_ph[:,n] + b_ph[n]) * pi
// =====================================================================
__global__ __launch_bounds__(256) void phases_kernel(const float* __restrict__ x,
                                                     const float* __restrict__ W_ph,
                                                     const float* __restrict__ b_ph,
                                                     float* __restrict__ phases) {
    __shared__ float xs[512];
    __shared__ float part[256];
    const int t = threadIdx.x;
    const size_t b = blockIdx.x;
    xs[t]       = x[b*512 + t];
    xs[t + 256] = x[b*512 + t + 256];
    __syncthreads();
    const int n2 = t & 15, g = t >> 4;
    float s = 0.0f;
#pragma unroll
    for (int j = 0; j < 32; j++) {
        int k = g*32 + j;
        s = fmaf(xs[k], W_ph[k*16 + n2], s);
    }
    part[t] = s;
    __syncthreads();
    if (t < 16) {
        float acc = b_ph[t];
#pragma unroll
        for (int g2 = 0; g2 < 16; g2++) acc += part[g2*16 + t];
        phases[b*16 + t] = tanhf(acc) * PI_F;
    }
}

// =====================================================================
// MEGA: per-b  encode -> metrics -> qkv -> complex attn -> out-proj -> means
// 256 threads/block, 8192 blocks. LDS arena 15808 floats (63232 B), overlaid:
//   ph1: br(0,2048) bi(2048) ir(4096,16x132) ii(6208) red(8320) red2(8576)
//        csn..phl(8832..8928) Urs(8928) Uis(9184)  [ends 9440]
//   ph2: Wrc(9472, 8x384) Wic(12544)               [ends 15616]
//   ph2 out (over 0..12672): qr2(0) qi2(2112) kr2(4224) ki2(6336) vr2(8448) vi2(10560)
//   ph3: wbuf(12672, 4x16x17=1088)                 [ends 13760]
//   ph4a out (over q): or_(0) oi_(2112)
//   ph4b: Wor(13760, 8x128) Woi(14784)             [ends 15808]
//   ph4b out (over k): attSr(4224) attSi(6336)
// amp and att pointers may alias (in-place per block) — no __restrict__.
// =====================================================================
__global__ __launch_bounds__(256) void mega_kernel(
    const float* ampR, const float* ampI,
    const float* __restrict__ phases,
    const float* __restrict__ Ur, const float* __restrict__ Ui,
    const float* __restrict__ Wqkv_r, const float* __restrict__ bqkv_r,
    const float* __restrict__ Wqkv_i, const float* __restrict__ bqkv_i,
    const float* __restrict__ Wout_r, const float* __restrict__ bout_r,
    const float* __restrict__ Wout_i, const float* __restrict__ bout_i,
    float* attR, float* attI,
    float* __restrict__ fid,
    float* __restrict__ attmR, float* __restrict__ attmI,
    float* __restrict__ pur_out, float* __restrict__ ent_out, float* __restrict__ pv_out)
{
    __shared__ float S[15808];
    float* br   = S;
    float* bi   = S + 2048;
    float* ir   = S + 4096;
    float* ii   = S + 6208;
    float* red  = S + 8320;
    float* red2 = S + 8576;
    float* csn  = S + 8832;
    float* snn  = S + 8848;
    float* invn = S + 8864;
    float* fnv  = S + 8880;
    float* purs = S + 8896;
    float* phl  = S + 8912;
    float* Urs  = S + 8928;
    float* Uis  = S + 9184;
    float* Wrc  = S + 9472;
    float* Wic  = S + 12544;
    float* qr2  = S;
    float* qi2  = S + 2112;
    float* kr2  = S + 4224;
    float* ki2  = S + 6336;
    float* vr2  = S + 8448;
    float* vi2  = S + 10560;
    float* wbuf = S + 12672;
    float* Wor  = S + 13760;
    float* Woi  = S + 14784;
    float* or_  = S;
    float* oi_  = S + 2112;
    float* attSr= S + 4224;
    float* attSi= S + 6336;

    const int t = threadIdx.x;
    const size_t b = blockIdx.x;

    // ================= phase 1: encode + metrics =================
    {
        const float4* aR = (const float4*)(ampR + b*2048);
        const float4* aI = (const float4*)(ampI + b*2048);
#pragma unroll
        for (int i = 0; i < 2; i++) {
            int c = t + i*256;
            *(float4*)&br[c*4] = aR[c];
            *(float4*)&bi[c*4] = aI[c];
        }
    }
    Urs[t] = Ur[t]; Uis[t] = Ui[t];
    if (t < 16) {
        float p = phases[b*16 + t];
        phl[t] = p; csn[t] = cosf(p); snn[t] = sinf(p);
    }
    __syncthreads();
    // rotate by phase
#pragma unroll
    for (int i = 0; i < 8; i++) {
        int idx = t + i*256;
        int n2 = idx >> 7;
        float ar = br[idx], ai = bi[idx];
        float cc = csn[n2], ss = snn[n2];
        br[idx] = ar*cc - ai*ss;
        bi[idx] = ar*ss + ai*cc;
    }
    __syncthreads();
    // per-n norms of state
    {
        const int n2 = t >> 4, g = t & 15;
        const float* pr  = &br[n2*128 + g*8];
        const float* pi2 = &bi[n2*128 + g*8];
        float s = 0.0f;
#pragma unroll
        for (int j = 0; j < 8; j++) s += pr[j]*pr[j] + pi2[j]*pi2[j];
        red[t] = s;
    }
    __syncthreads();
    if (t < 16) {
        float s = 0.0f;
#pragma unroll
        for (int g2 = 0; g2 < 16; g2++) s += red[t*16 + g2];
        invn[t] = 1.0f / sqrtf(s + 1e-8f);
    }
    __syncthreads();
#pragma unroll
    for (int i = 0; i < 8; i++) {
        int idx = t + i*256;
        float iv = invn[idx >> 7];
        br[idx] *= iv; bi[idx] *= iv;
    }
    __syncthreads();
    // interference: ir/ii[n][d] = sum_m state[m,d] * U[m,n]  (complex)
#pragma unroll
    for (int rep = 0; rep < 8; rep++) {
        int o = t + rep*256;
        int n2 = o >> 7, d = o & 127;
        float ar = 0.0f, ai = 0.0f;
#pragma unroll
        for (int m = 0; m < 16; m++) {
            float vr = br[m*128 + d], vi = bi[m*128 + d];
            float ur = Urs[m*16 + n2], ui = Uis[m*16 + n2];
            ar += vr*ur - vi*ui;
            ai += vr*ui + vi*ur;
        }
        ir[n2*132 + d] = ar; ii[n2*132 + d] = ai;
    }
    __syncthreads();
    // purity / frobenius per n
    {
        const int n2 = t >> 4, g = t & 15;
        float s2 = 0.0f, s4 = 0.0f;
#pragma unroll
        for (int j = 0; j < 8; j++) {
            float xr = ir[n2*132 + g*8+j], xi = ii[n2*132 + g*8+j];
            float m2 = xr*xr + xi*xi;
            s2 += m2; s4 += m2*m2;
        }
        red[t] = s2; red2[t] = s4;
    }
    __syncthreads();
    if (t < 16) {
        float S2 = 0.0f, S4 = 0.0f;
#pragma unroll
        for (int g2 = 0; g2 < 16; g2++) { S2 += red[t*16+g2]; S4 += red2[t*16+g2]; }
        purs[t] = S4 / (S2*S2 + 1e-8f);
        fnv[t] = sqrtf(S2 + 1e-8f);
    }
    __syncthreads();
    if (t == 0) {
        float pb = 0.0f;
#pragma unroll
        for (int n2 = 0; n2 < 16; n2++) pb += purs[n2];
        pb *= (1.0f/16.0f);
        atomicAdd(pur_out, pb * INV_B);
        atomicAdd(ent_out, -logf(pb + 1e-8f) * INV_B);
    }
    if (t == 1) {
        float mean = 0.0f;
#pragma unroll
        for (int n2 = 0; n2 < 16; n2++) mean += phl[n2];
        mean *= (1.0f/16.0f);
        float var = 0.0f;
#pragma unroll
        for (int n2 = 0; n2 < 16; n2++) { float dv = phl[n2] - mean; var += dv*dv; }
        var *= (1.0f/15.0f);
        atomicAdd(pv_out, var * INV_B);
    }
    // fidelity (one (i,j) pair per thread)
    {
        const int i2 = t >> 4, j2 = t & 15;
        float Rt = 0.0f, It = 0.0f;
#pragma unroll
        for (int d0 = 0; d0 < 128; d0 += 4) {
            float4 xr = *(const float4*)&ir[i2*132 + d0];
            float4 xi = *(const float4*)&ii[i2*132 + d0];
            float4 yr = *(const float4*)&ir[j2*132 + d0];
            float4 yi = *(const float4*)&ii[j2*132 + d0];
            Rt += xr.x*yr.x + xi.x*yi.x;  It += xr.x*yi.x - xi.x*yr.x;
            Rt += xr.y*yr.y + xi.y*yi.y;  It += xr.y*yi.y - xi.y*yr.y;
            Rt += xr.z*yr.z + xi.z*yi.z;  It += xr.z*yi.z - xi.z*yr.z;
            Rt += xr.w*yr.w + xi.w*yi.w;  It += xr.w*yi.w - xi.w*yr.w;
        }
        float inv = 1.0f / (fnv[i2]*fnv[j2]);
        float F = (Rt*Rt + It*It) * inv * inv;
        F = fminf(fmaxf(F, 0.0f), 1.0f);
        fid[b*256 + t] = F;
    }

    // ================= phase 2: qkv projections (real GEMMs) =================
    // qkv_r[n,c] = sum_d ir[n,d]*Wqkv_r[d,c] + bqkv_r[c]; qkv_i likewise from ii/W_i
    const int cg = t >> 4, nn = t & 15;
    float aq[24], bq[24];
#pragma unroll
    for (int j = 0; j < 24; j++) { aq[j] = 0.0f; bq[j] = 0.0f; }
    for (int d0 = 0; d0 < 128; d0 += 8) {
        __syncthreads();   // protect W chunk reuse (and first-iter: fid reads done)
#pragma unroll
        for (int i = 0; i < 3; i++) {
            int idx = (t + i*256) * 4;
            *(float4*)&Wrc[idx] = *(const float4*)&Wqkv_r[d0*384 + idx];
            *(float4*)&Wic[idx] = *(const float4*)&Wqkv_i[d0*384 + idx];
        }
        __syncthreads();
#pragma unroll
        for (int dd = 0; dd < 8; dd++) {
            const float arr = ir[nn*132 + d0 + dd];
            const float aii = ii[nn*132 + d0 + dd];
#pragma unroll
            for (int s2 = 0; s2 < 6; s2++) {
                const float4 wr4 = *(const float4*)&Wrc[dd*384 + cg*4 + 64*s2];
                const float4 wi4 = *(const float4*)&Wic[dd*384 + cg*4 + 64*s2];
                aq[s2*4+0] = fmaf(arr, wr4.x, aq[s2*4+0]);
                aq[s2*4+1] = fmaf(arr, wr4.y, aq[s2*4+1]);
                aq[s2*4+2] = fmaf(arr, wr4.z, aq[s2*4+2]);
                aq[s2*4+3] = fmaf(arr, wr4.w, aq[s2*4+3]);
                bq[s2*4+0] = fmaf(aii, wi4.x, bq[s2*4+0]);
                bq[s2*4+1] = fmaf(aii, wi4.y, bq[s2*4+1]);
                bq[s2*4+2] = fmaf(aii, wi4.z, bq[s2*4+2]);
                bq[s2*4+3] = fmaf(aii, wi4.w, bq[s2*4+3]);
            }
        }
    }
    __syncthreads();   // all ir/ii + W reads complete; overlay q/k/v over 0..12672
#pragma unroll
    for (int s2 = 0; s2 < 6; s2++) {
#pragma unroll
        for (int j = 0; j < 4; j++) {
            const int c = cg*4 + 64*s2 + j;
            float qvr = aq[s2*4+j] + bqkv_r[c];
            float qvi = bq[s2*4+j] + bqkv_i[c];
            if (s2 < 2)      { qr2[nn*132 + c]         = qvr; qi2[nn*132 + c]         = qvi; }
            else if (s2 < 4) { kr2[nn*132 + (c-128)]   = qvr; ki2[nn*132 + (c-128)]   = qvi; }
            else             { vr2[nn*132 + (c-256)]   = qvr; vi2[nn*132 + (c-256)]   = qvi; }
        }
    }
    __syncthreads();

    // ================= phase 3: scores + magnitude softmax =================
    {
        const int nq = t >> 4, m = t & 15;
#pragma unroll
        for (int h = 0; h < 4; h++) {
            float ar = 0.0f, ai = 0.0f;
            const int bqo = h*32;
#pragma unroll
            for (int d0 = 0; d0 < 32; d0 += 4) {
                float4 q_r = *(const float4*)&qr2[nq*132 + bqo + d0];
                float4 k_r = *(const float4*)&kr2[m*132  + bqo + d0];
                float4 q_i = *(const float4*)&qi2[nq*132 + bqo + d0];
                float4 k_i = *(const float4*)&ki2[m*132  + bqo + d0];
                ar += q_r.x*k_r.x + q_i.x*k_i.x + q_r.y*k_r.y + q_i.y*k_i.y
                    + q_r.z*k_r.z + q_i.z*k_i.z + q_r.w*k_r.w + q_i.w*k_i.w;
                ai += q_i.x*k_r.x - q_r.x*k_i.x + q_i.y*k_r.y - q_r.y*k_i.y
                    + q_i.z*k_r.z - q_r.z*k_i.z + q_i.w*k_r.w - q_r.w*k_i.w;
            }
            wbuf[h*272 + nq*17 + m] = sqrtf(ar*ar + ai*ai) * SCALE_F;
        }
    }
    __syncthreads();
    if (t < 64) {
        const int h = t >> 4, n2 = t & 15;
        float* row = &wbuf[h*272 + n2*17];
        float mx = row[0];
#pragma unroll
        for (int k = 1; k < 16; k++) mx = fmaxf(mx, row[k]);
        float ev[16];
        float sum = 0.0f;
#pragma unroll
        for (int k = 0; k < 16; k++) { ev[k] = expf(row[k] - mx); sum += ev[k]; }
        float inv = 1.0f / sum;
#pragma unroll
        for (int k = 0; k < 16; k++) row[k] = ev[k] * inv;
    }
    __syncthreads();

    // ================= phase 4a: per-head PV -> o in LDS =================
    {
        const int og = t >> 4, n2 = t & 15;
        const int hh = og >> 2;
        float por[8] = {0,0,0,0,0,0,0,0}, poi[8] = {0,0,0,0,0,0,0,0};
#pragma unroll
        for (int m2 = 0; m2 < 16; m2++) {
            float w = wbuf[hh*272 + n2*17 + m2];
            float4 v0 = *(const float4*)&vr2[m2*132 + og*8];
            float4 v1 = *(const float4*)&vr2[m2*132 + og*8 + 4];
            float4 u0 = *(const float4*)&vi2[m2*132 + og*8];
            float4 u1 = *(const float4*)&vi2[m2*132 + og*8 + 4];
            por[0] = fmaf(w, v0.x, por[0]); por[1] = fmaf(w, v0.y, por[1]);
            por[2] = fmaf(w, v0.z, por[2]); por[3] = fmaf(w, v0.w, por[3]);
            por[4] = fmaf(w, v1.x, por[4]); por[5] = fmaf(w, v1.y, por[5]);
            por[6] = fmaf(w, v1.z, por[6]); por[7] = fmaf(w, v1.w, por[7]);
            poi[0] = fmaf(w, u0.x, poi[0]); poi[1] = fmaf(w, u0.y, poi[1]);
            poi[2] = fmaf(w, u0.z, poi[2]); poi[3] = fmaf(w, u0.w, poi[3]);
            poi[4] = fmaf(w, u1.x, poi[4]); poi[5] = fmaf(w, u1.y, poi[5]);
            poi[6] = fmaf(w, u1.z, poi[6]); poi[7] = fmaf(w, u1.w, poi[7]);
        }
        // write o over dead q region (disjoint from wbuf/v being read by others)
#pragma unroll
        for (int j = 0; j < 8; j++) {
            or_[n2*132 + og*8 + j] = por[j];
            oi_[n2*132 + og*8 + j] = poi[j];
        }
    }
    __syncthreads();

    // ================= phase 4b: att = o @ Wout + bias =================
    {
        const int og = t >> 4, n2 = t & 15;
        float atr[8] = {0,0,0,0,0,0,0,0}, ati[8] = {0,0,0,0,0,0,0,0};
        for (int d0 = 0; d0 < 128; d0 += 8) {
            __syncthreads();   // protect Wout chunk reuse
            *(float4*)&Wor[t*4] = *(const float4*)&Wout_r[d0*128 + t*4];
            *(float4*)&Woi[t*4] = *(const float4*)&Wout_i[d0*128 + t*4];
            __syncthreads();
#pragma unroll
            for (int dd = 0; dd < 8; dd++) {
                const float a_r = or_[n2*132 + d0 + dd];
                const float a_i = oi_[n2*132 + d0 + dd];
                float4 w0 = *(const float4*)&Wor[dd*128 + og*8];
                float4 w1 = *(const float4*)&Wor[dd*128 + og*8 + 4];
                float4 u0 = *(const float4*)&Woi[dd*128 + og*8];
                float4 u1 = *(const float4*)&Woi[dd*128 + og*8 + 4];
                atr[0] = fmaf(a_r, w0.x, atr[0]); atr[1] = fmaf(a_r, w0.y, atr[1]);
                atr[2] = fmaf(a_r, w0.z, atr[2]); atr[3] = fmaf(a_r, w0.w, atr[3]);
                atr[4] = fmaf(a_r, w1.x, atr[4]); atr[5] = fmaf(a_r, w1.y, atr[5]);
                atr[6] = fmaf(a_r, w1.z, atr[6]); atr[7] = fmaf(a_r, w1.w, atr[7]);
                ati[0] = fmaf(a_i, u0.x, ati[0]); ati[1] = fmaf(a_i, u0.y, ati[1]);
                ati[2] = fmaf(a_i, u0.z, ati[2]); ati[3] = fmaf(a_i, u0.w, ati[3]);
                ati[4] = fmaf(a_i, u1.x, ati[4]); ati[5] = fmaf(a_i, u1.y, ati[5]);
                ati[6] = fmaf(a_i, u1.z, ati[6]); ati[7] = fmaf(a_i, u1.w, ati[7]);
            }
        }
        const float4 br0 = *(const float4*)&bout_r[og*8];
        const float4 br1 = *(const float4*)&bout_r[og*8 + 4];
        const float4 bi0 = *(const float4*)&bout_i[og*8];
        const float4 bi1 = *(const float4*)&bout_i[og*8 + 4];
        float4 o0 = make_float4(atr[0]+br0.x, atr[1]+br0.y, atr[2]+br0.z, atr[3]+br0.w);
        float4 o1 = make_float4(atr[4]+br1.x, atr[5]+br1.y, atr[6]+br1.z, atr[7]+br1.w);
        float4 e0 = make_float4(ati[0]+bi0.x, ati[1]+bi0.y, ati[2]+bi0.z, ati[3]+bi0.w);
        float4 e1 = make_float4(ati[4]+bi1.x, ati[5]+bi1.y, ati[6]+bi1.z, ati[7]+bi1.w);
        size_t gbase = b*2048 + (size_t)n2*128 + og*8;
        *(float4*)&attR[gbase]     = o0;
        *(float4*)&attR[gbase + 4] = o1;
        *(float4*)&attI[gbase]     = e0;
        *(float4*)&attI[gbase + 4] = e1;
        // stash for means (over dead k region; disjoint from or_/Wor being read)
        *(float4*)&attSr[n2*132 + og*8]     = o0;
        *(float4*)&attSr[n2*132 + og*8 + 4] = o1;
        *(float4*)&attSi[n2*132 + og*8]     = e0;
        *(float4*)&attSi[n2*132 + og*8 + 4] = e1;
    }
    __syncthreads();

    // ================= phase 5: means over n =================
    if (t < 128) {
        const int d = t;
        float s = 0.0f;
#pragma unroll
        for (int n2 = 0; n2 < 16; n2++) s += attSr[n2*132 + d];
        attmR[b*128 + d] = s * (1.0f/16.0f);
    } else {
        const int d = t - 128;
        float s = 0.0f;
#pragma unroll
        for (int n2 = 0; n2 < 16; n2++) s += attSi[n2*132 + d];
        attmI[b*128 + d] = s * (1.0f/16.0f);
    }
}

// =====================================================================
// measurement. grid = (B/32, 16). Each block: 32 b-rows, one n.
// MODE 0: store mR/mI + mag; MODE 1: mag only; MODE 2: weighted atomic accum
// =====================================================================
template<int MODE>
__global__ __launch_bounds__(256) void measure_kernel(const float* __restrict__ attR,
                                                      const float* __restrict__ attI,
                                                      const float* __restrict__ M_r,
                                                      const float* __restrict__ M_i,
                                                      float* __restrict__ mR,
                                                      float* __restrict__ mI,
                                                      float* __restrict__ mag,
                                                      const float* __restrict__ probs,
                                                      float* __restrict__ orAcc,
                                                      float* __restrict__ oiAcc) {
    __shared__ float ar_s[32*128];
    __shared__ float ai_s[32*128];
    const int t = threadIdx.x;
    const size_t b0 = (size_t)blockIdx.x * 32;
    const int n = blockIdx.y;
#pragma unroll
    for (int i = 0; i < 4; i++) {
        int c = t + i*256;
        int row = c >> 5, d4 = (c & 31) << 2;
        *(float4*)&ar_s[row*128 + d4] = *(const float4*)&attR[((b0+row)*16 + n)*128 + d4];
        *(float4*)&ai_s[row*128 + d4] = *(const float4*)&attI[((b0+row)*16 + n)*128 + d4];
    }
    __syncthreads();
    const int ol = t & 63;
    const int rg = t >> 6;
    const int obase = ol * 4;
    float mr[8][4], mi[8][4];
#pragma unroll
    for (int i = 0; i < 8; i++)
#pragma unroll
        for (int j = 0; j < 4; j++) { mr[i][j] = 0.0f; mi[i][j] = 0.0f; }
    const float* Mrp = M_r + (size_t)n*DD*OO;
    const float* Mip = M_i + (size_t)n*DD*OO;
    for (int k0 = 0; k0 < 128; k0 += 4) {
        float4 Mr4[4], Mi4[4];
#pragma unroll
        for (int u = 0; u < 4; u++) {
            Mr4[u] = *(const float4*)&Mrp[(k0+u)*256 + obase];
            Mi4[u] = *(const float4*)&Mip[(k0+u)*256 + obase];
        }
#pragma unroll
        for (int r8 = 0; r8 < 8; r8++) {
            const int row = rg*8 + r8;
            float4 a4 = *(const float4*)&ar_s[row*128 + k0];
            float4 c4 = *(const float4*)&ai_s[row*128 + k0];
            float arv[4] = {a4.x, a4.y, a4.z, a4.w};
            float aiv[4] = {c4.x, c4.y, c4.z, c4.w};
#pragma unroll
            for (int u = 0; u < 4; u++) {
                float ar = arv[u], ai = aiv[u];
                mr[r8][0] = fmaf(ar, Mr4[u].x, mr[r8][0]); mr[r8][0] = fmaf(-ai, Mi4[u].x, mr[r8][0]);
                mr[r8][1] = fmaf(ar, Mr4[u].y, mr[r8][1]); mr[r8][1] = fmaf(-ai, Mi4[u].y, mr[r8][1]);
                mr[r8][2] = fmaf(ar, Mr4[u].z, mr[r8][2]); mr[r8][2] = fmaf(-ai, Mi4[u].z, mr[r8][2]);
                mr[r8][3] = fmaf(ar, Mr4[u].w, mr[r8][3]); mr[r8][3] = fmaf(-ai, Mi4[u].w, mr[r8][3]);
                mi[r8][0] = fmaf(ar, Mi4[u].x, mi[r8][0]); mi[r8][0] = fmaf( ai, Mr4[u].x, mi[r8][0]);
                mi[r8][1] = fmaf(ar, Mi4[u].y, mi[r8][1]); mi[r8][1] = fmaf( ai, Mr4[u].y, mi[r8][1]);
                mi[r8][2] = fmaf(ar, Mi4[u].z, mi[r8][2]); mi[r8][2] = fmaf( ai, Mr4[u].z, mi[r8][2]);
                mi[r8][3] = fmaf(ar, Mi4[u].w, mi[r8][3]); mi[r8][3] = fmaf( ai, Mr4[u].w, mi[r8][3]);
            }
        }
    }
#pragma unroll
    for (int r8 = 0; r8 < 8; r8++) {
        const int row = rg*8 + r8;
        if constexpr (MODE == 0) {
            size_t base = ((b0+row)*16 + n)*256 + obase;
            *(float4*)&mR[base] = make_float4(mr[r8][0], mr[r8][1], mr[r8][2], mr[r8][3]);
            *(float4*)&mI[base] = make_float4(mi[r8][0], mi[r8][1], mi[r8][2], mi[r8][3]);
        }
        if constexpr (MODE == 2) {
            float p = probs[(b0+row)*16 + n];
            size_t abase = (b0+row)*256 + obase;
#pragma unroll
            for (int u = 0; u < 4; u++) {
                atomicAdd(&orAcc[abase + u], p * mr[r8][u]);
                atomicAdd(&oiAcc[abase + u], p * mi[r8][u]);
            }
        } else {
            float p = 0.0f;
#pragma unroll
            for (int u = 0; u < 4; u++)
                p += sqrtf(mr[r8][u]*mr[r8][u] + mi[r8][u]*mi[r8][u]);
#pragma unroll
            for (int s = 32; s > 0; s >>= 1) p += __shfl_down(p, s, 64);
            if (ol == 0) mag[(b0+row)*16 + n] = p * (1.0f/256.0f);
        }
    }
}

// =====================================================================
// K7 (big path): probs (softmax over n of mag) + classical output
// =====================================================================
__global__ __launch_bounds__(256) void final_kernel(const float* __restrict__ mR,
                                                    const float* __restrict__ mI,
                                                    const float* __restrict__ mag,
                                                    float* __restrict__ cls,
                                                    float* __restrict__ probs) {
    __shared__ float pr[16];
    const size_t b = blockIdx.x;
    const int t = threadIdx.x;
    if (t == 0) {
        float v[16];
        float mx = -1e30f;
#pragma unroll
        for (int n2 = 0; n2 < 16; n2++) { v[n2] = mag[b*16 + n2]; mx = fmaxf(mx, v[n2]); }
        float sum = 0.0f;
#pragma unroll
        for (int n2 = 0; n2 < 16; n2++) { float e = expf(v[n2] - mx); pr[n2] = e; sum += e; }
        float inv = 1.0f / sum;
#pragma unroll
        for (int n2 = 0; n2 < 16; n2++) pr[n2] *= inv;
    }
    __syncthreads();
    if (t < 16) probs[b*16 + t] = pr[t];
    float orv = 0.0f, oiv = 0.0f;
#pragma unroll
    for (int n2 = 0; n2 < 16; n2++) {
        float p = pr[n2];
        size_t base = (b*16 + n2)*256 + t;
        orv = fmaf(mR[base], p, orv);
        oiv = fmaf(mI[base], p, oiv);
    }
    cls[b*256 + t] = sqrtf(orv*orv + oiv*oiv);
}

// =====================================================================
// small path: probs from mag; classical from accumulators
// =====================================================================
__global__ __launch_bounds__(256) void probs_kernel(const float* __restrict__ mag,
                                                    float* __restrict__ probs) {
    const int b = blockIdx.x*256 + threadIdx.x;   // grid 32 -> 8192 threads
    float v[16];
    float mx = -1e30f;
#pragma unroll
    for (int n2 = 0; n2 < 16; n2++) { v[n2] = mag[b*16 + n2]; mx = fmaxf(mx, v[n2]); }
    float sum = 0.0f;
#pragma unroll
    for (int n2 = 0; n2 < 16; n2++) { v[n2] = expf(v[n2] - mx); sum += v[n2]; }
    float inv = 1.0f / sum;
#pragma unroll
    for (int n2 = 0; n2 < 16; n2++) probs[b*16 + n2] = v[n2] * inv;
}

__global__ __launch_bounds__(256) void classical_kernel(const float* __restrict__ orAcc,
                                                        const float* __restrict__ oiAcc,
                                                        float* __restrict__ cls) {
    const size_t i = (size_t)blockIdx.x*256 + threadIdx.x;
    float a = orAcc[i], c = oiAcc[i];
    cls[i] = sqrtf(a*a + c*c);
}

// =====================================================================
// host launcher
// =====================================================================
extern "C" void kernel_launch(void* const* d_in, const int* in_sizes, int n_in,
                              void* d_out, int out_size, void* d_ws, size_t ws_size,
                              hipStream_t stream) {
    const float* x        = (const float*)d_in[0];
    const float* W_amp_r  = (const float*)d_in[1];
    const float* b_amp_r  = (const float*)d_in[2];
    const float* W_amp_i  = (const float*)d_in[3];
    const float* b_amp_i  = (const float*)d_in[4];
    const float* W_ph     = (const float*)d_in[5];
    const float* b_ph     = (const float*)d_in[6];
    const float* A_param  = (const float*)d_in[7];
    const float* Wqkv_r   = (const float*)d_in[8];
    const float* bqkv_r   = (const float*)d_in[9];
    const float* Wqkv_i   = (const float*)d_in[10];
    const float* bqkv_i   = (const float*)d_in[11];
    const float* Wout_r   = (const float*)d_in[12];
    const float* bout_r   = (const float*)d_in[13];
    const float* Wout_i   = (const float*)d_in[14];
    const float* bout_i   = (const float*)d_in[15];
    const float* M_r      = (const float*)d_in[16];
    const float* M_i      = (const float*)d_in[17];
    float* out = (float*)d_out;
    float* ws  = (float*)d_ws;

    // amp region (reused in-place as att): 2 x 16777216 floats
    float* ampR = ws;
    float* ampI = ws + 16777216;
    float* attR = ampR;
    float* attI = ampI;

    const bool big = ws_size >= (size_t)403703808ull;   // 404 MB path
    float *mRp = nullptr, *mIp = nullptr, *orA = nullptr, *oiA = nullptr;
    float *phases, *mag, *UrP, *UiP;
    if (big) {
        mRp    = ws + 33554432;      // 33554432 floats
        mIp    = ws + 67108864;      // 33554432 floats
        phases = ws + 100663296;     // 131072
        mag    = ws + 100794368;     // 131072
        UrP    = ws + 100925440;     // 256
        UiP    = ws + 100925696;     // 256  (end 100925952 fl = 403,703,808 B)
    } else {
        orA    = ws + 33554432;      // 2097152
        oiA    = ws + 35651584;      // 2097152
        phases = ws + 37748736;      // 131072
        mag    = ws + 37879808;      // 131072
        UrP    = ws + 38010880;      // 256
        UiP    = ws + 38011136;      // 256  (end 38011392 fl = 152,045,568 B)
    }

    // zero atomic-accumulated outputs / accumulators
    hipMemsetAsync(out + OFF_PUR, 0, 2*sizeof(float), stream);
    hipMemsetAsync(out + OFF_PV,  0, sizeof(float), stream);
    if (!big) hipMemsetAsync(orA, 0, 2ull*2097152ull*sizeof(float), stream);

    cayley_kernel<<<1, 256, 0, stream>>>(A_param, UrP, UiP);

    gemm_f32<<<dim3(64, 16), 256, 0, stream>>>(x, 512, W_amp_r, 2048, b_amp_r, ampR, 2048, 512);
    gemm_f32<<<dim3(64, 16), 256, 0, stream>>>(x, 512, W_amp_i, 2048, b_amp_i, ampI, 2048, 512);
    phases_kernel<<<8192, 256, 0, stream>>>(x, W_ph, b_ph, phases);

    mega_kernel<<<8192, 256, 0, stream>>>(ampR, ampI, phases, UrP, UiP,
                                          Wqkv_r, bqkv_r, Wqkv_i, bqkv_i,
                                          Wout_r, bout_r, Wout_i, bout_i,
                                          attR, attI,
                                          out + OFF_FID, out + OFF_ATTRM, out + OFF_ATTIM,
                                          out + OFF_PUR, out + OFF_ENT, out + OFF_PV);

    if (big) {
        measure_kernel<0><<<dim3(256, 16), 256, 0, stream>>>(attR, attI, M_r, M_i,
                                                             mRp, mIp, mag, nullptr, nullptr, nullptr);
        final_kernel<<<8192, 256, 0, stream>>>(mRp, mIp, mag, out + OFF_CLASS, out + OFF_PROBS);
    } else {
        measure_kernel<1><<<dim3(256, 16), 256, 0, stream>>>(attR, attI, M_r, M_i,
                                                             nullptr, nullptr, mag, nullptr, nullptr, nullptr);
        probs_kernel<<<32, 256, 0, stream>>>(mag, out + OFF_PROBS);
        measure_kernel<2><<<dim3(256, 16), 256, 0, stream>>>(attR, attI, M_r, M_i,
                                                             nullptr, nullptr, nullptr,
                                                             out + OFF_PROBS, orA, oiA);
        classical_kernel<<<8192, 256, 0, stream>>>(orA, oiA, out + OFF_CLASS);
    }
}

// Round 6
// 3206.845 us; speedup vs baseline: 1.0307x; 1.0307x over previous
//
#include <hip/hip_runtime.h>
#include <math.h>

// ---------------- problem constants ----------------
#define B_ 8192
#define IN_ 512
#define NQ 16
#define DD 128
#define OO 256
#define PI_F 3.14159274101257324f
#define INV_B (1.0f/8192.0f)
#define SCALE_F 0.176776695296636881f   // 1/sqrt(32)

// ---------------- d_out offsets (floats) ----------------
#define OFF_CLASS 0
#define OFF_PROBS 2097152
#define OFF_ATTRM 2228224
#define OFF_ATTIM 3276800
#define OFF_PUR   4325376
#define OFF_ENT   4325377
#define OFF_FID   4325378
#define OFF_PV    6422530

// =====================================================================
// K0: Cayley transform  U = (I - iA)^-1 (I + iA), A = A_param - A_param^T
// =====================================================================
__global__ __launch_bounds__(256) void cayley_kernel(const float* __restrict__ A_param,
                                                     float* __restrict__ Ur,
                                                     float* __restrict__ Ui) {
    __shared__ float Mr[16][17], Mi[16][17], Rr[16][17], Ri[16][17];
    const int t = threadIdx.x;
    const int r = t >> 4, c = t & 15;
    float a = A_param[r*16 + c] - A_param[c*16 + r];
    Mr[r][c] = (r == c) ? 1.0f : 0.0f;
    Mi[r][c] = -a;
    Rr[r][c] = (r == c) ? 1.0f : 0.0f;
    Ri[r][c] = a;
    __syncthreads();
    for (int p = 0; p < 16; p++) {
        float prr = Mr[p][p], pii = Mi[p][p];
        __syncthreads();
        if (r == p) {
            float inv = 1.0f / (prr*prr + pii*pii);
            float mr0 = Mr[p][c], mi0 = Mi[p][c];
            Mr[p][c] = (mr0*prr + mi0*pii) * inv;
            Mi[p][c] = (mi0*prr - mr0*pii) * inv;
            float rr0 = Rr[p][c], ri0 = Ri[p][c];
            Rr[p][c] = (rr0*prr + ri0*pii) * inv;
            Ri[p][c] = (ri0*prr - rr0*pii) * inv;
        }
        __syncthreads();
        float fr = Mr[r][p], fi = Mi[r][p];
        float mpr = Mr[p][c], mpi = Mi[p][c];
        float rpr = Rr[p][c], rpi = Ri[p][c];
        __syncthreads();
        if (r != p) {
            Mr[r][c] -= fr*mpr - fi*mpi;
            Mi[r][c] -= fr*mpi + fi*mpr;
            Rr[r][c] -= fr*rpr - fi*rpi;
            Ri[r][c] -= fr*rpi + fi*rpr;
        }
        __syncthreads();
    }
    Ur[t] = Rr[r][c];
    Ui[t] = Ri[r][c];
}

// =====================================================================
// Generic fp32 GEMM: C[M x N] = A[M x K] @ W[K x N] + bias  (128x128x32)
// =====================================================================
__global__ __launch_bounds__(256) void gemm_f32(const float* __restrict__ A, int lda,
                                                const float* __restrict__ W, int ldw,
                                                const float* __restrict__ bias,
                                                float* __restrict__ C, int ldc, int K) {
    __shared__ float As[32][132];
    __shared__ float Bs[32][132];
    const int t = threadIdx.x;
    const int tm = t >> 4, tn = t & 15;
    const size_t r0 = (size_t)blockIdx.x * 128;
    const int c0 = blockIdx.y * 128;
    float acc[8][8];
#pragma unroll
    for (int i = 0; i < 8; i++)
#pragma unroll
        for (int j = 0; j < 8; j++) acc[i][j] = 0.0f;

    for (int k0 = 0; k0 < K; k0 += 32) {
#pragma unroll
        for (int i = 0; i < 4; i++) {
            int idx = t + i*256;
            int mm = idx >> 3, kq = (idx & 7) << 2;
            float4 va = *(const float4*)&A[(r0 + mm)*lda + (k0 + kq)];
            As[kq+0][mm] = va.x; As[kq+1][mm] = va.y;
            As[kq+2][mm] = va.z; As[kq+3][mm] = va.w;
        }
#pragma unroll
        for (int i = 0; i < 4; i++) {
            int idx = t + i*256;
            int kk = idx >> 5, cq = (idx & 31) << 2;
            *(float4*)&Bs[kk][cq] = *(const float4*)&W[(size_t)(k0+kk)*ldw + (c0+cq)];
        }
        __syncthreads();
#pragma unroll
        for (int kk = 0; kk < 32; kk++) {
            float4 a0 = *(const float4*)&As[kk][tm*4];
            float4 a1 = *(const float4*)&As[kk][64 + tm*4];
            float4 b0 = *(const float4*)&Bs[kk][tn*4];
            float4 b1 = *(const float4*)&Bs[kk][64 + tn*4];
            float av[8] = {a0.x,a0.y,a0.z,a0.w,a1.x,a1.y,a1.z,a1.w};
            float bv[8] = {b0.x,b0.y,b0.z,b0.w,b1.x,b1.y,b1.z,b1.w};
#pragma unroll
            for (int i = 0; i < 8; i++)
#pragma unroll
                for (int j = 0; j < 8; j++)
                    acc[i][j] = fmaf(av[i], bv[j], acc[i][j]);
        }
        __syncthreads();
    }
#pragma unroll
    for (int ri = 0; ri < 2; ri++)
#pragma unroll
    for (int i = 0; i < 4; i++) {
        size_t row = r0 + ri*64 + tm*4 + i;
#pragma unroll
        for (int ci = 0; ci < 2; ci++) {
            int col = c0 + ci*64 + tn*4;
            float4 bb = *(const float4*)&bias[col];
            float4 v;
            v.x = acc[ri*4+i][ci*4+0] + bb.x;
            v.y = acc[ri*4+i][ci*4+1] + bb.y;
            v.z = acc[ri*4+i][ci*4+2] + bb.z;
            v.w = acc[ri*4+i][ci*4+3] + bb.w;
            *(float4*)&C[row*ldc + col] = v;
        }
    }
}

// =====================================================================
// K1b: phases[b,n] = tanh(x[b]·W_ph[:,n] + b_ph[n]) * pi
// =====================================================================
__global__ __launch_bounds__(256) void phases_kernel(const float* __restrict__ x,
                                                     const float* __restrict__ W_ph,
                                                     const float* __restrict__ b_ph,
                                                     float* __restrict__ phases) {
    __shared__ float xs[512];
    __shared__ float part[256];
    const int t = threadIdx.x;
    const size_t b = blockIdx.x;
    xs[t]       = x[b*512 + t];
    xs[t + 256] = x[b*512 + t + 256];
    __syncthreads();
    const int n2 = t & 15, g = t >> 4;
    float s = 0.0f;
#pragma unroll
    for (int j = 0; j < 32; j++) {
        int k = g*32 + j;
        s = fmaf(xs[k], W_ph[k*16 + n2], s);
    }
    part[t] = s;
    __syncthreads();
    if (t < 16) {
        float acc = b_ph[t];
#pragma unroll
        for (int g2 = 0; g2 < 16; g2++) acc += part[g2*16 + t];
        phases[b*16 + t] = tanhf(acc) * PI_F;
    }
}

// =====================================================================
// MEGA: per-b  encode -> metrics -> qkv -> complex attn -> out-proj -> means
// 256 threads/block, 8192 blocks. LDS arena 13568 floats (54272 B => 3 blk/CU):
//   ph1: ir(0,16x132) ii(2112) br(4224,2048) bi(6272) red(8320) red2(8576)
//        csn..phl(8832..8928) Urs(8928) Uis(9184)   [ends 9440]
//   ph2: Wrc(4224, 4x384=1536) Wic(5760)            [ends 7296; ir/ii live]
//   ph2 out (over 0..12480, stride 130): qr2(0) qi2(2080) kr2(4160) ki2(6240)
//        vr2(8320) vi2(10400)
//   ph3: wbuf(12480, 4x272=1088)                    [ends 13568]
//   ph4a out (over q): or_(0) oi_(2080)
//   ph4b: Wor(4160, 8x128=1024) Woi(5184)           [over dead k region]
//   ph4b out (over v): attSr(8320) attSi(10400)
// amp and att pointers alias (in-place per block) — no __restrict__.
// =====================================================================
__global__ __launch_bounds__(256, 3) void mega_kernel(
    const float* ampR, const float* ampI,
    const float* __restrict__ phases,
    const float* __restrict__ Ur, const float* __restrict__ Ui,
    const float* __restrict__ Wqkv_r, const float* __restrict__ bqkv_r,
    const float* __restrict__ Wqkv_i, const float* __restrict__ bqkv_i,
    const float* __restrict__ Wout_r, const float* __restrict__ bout_r,
    const float* __restrict__ Wout_i, const float* __restrict__ bout_i,
    float* attR, float* attI,
    float* __restrict__ fid,
    float* __restrict__ attmR, float* __restrict__ attmI,
    float* __restrict__ pur_out, float* __restrict__ ent_out, float* __restrict__ pv_out)
{
    __shared__ float S[13568];
    float* ir   = S;            // 16 x 132
    float* ii   = S + 2112;     // 16 x 132
    float* br   = S + 4224;     // 2048
    float* bi   = S + 6272;     // 2048
    float* red  = S + 8320;
    float* red2 = S + 8576;
    float* csn  = S + 8832;
    float* snn  = S + 8848;
    float* invn = S + 8864;
    float* fnv  = S + 8880;
    float* purs = S + 8896;
    float* phl  = S + 8912;
    float* Urs  = S + 8928;
    float* Uis  = S + 9184;
    float* Wrc  = S + 4224;     // ph2 chunk: 4 x 384
    float* Wic  = S + 5760;
    float* qr2  = S;            // 16 x 130
    float* qi2  = S + 2080;
    float* kr2  = S + 4160;
    float* ki2  = S + 6240;
    float* vr2  = S + 8320;
    float* vi2  = S + 10400;
    float* wbuf = S + 12480;    // 4 x 272
    float* or_  = S;            // 16 x 130
    float* oi_  = S + 2080;
    float* Wor  = S + 4160;     // ph4b chunk: 8 x 128
    float* Woi  = S + 5184;
    float* attSr= S + 8320;     // 16 x 130
    float* attSi= S + 10400;

    const int t = threadIdx.x;
    const size_t b = blockIdx.x;

    // ================= phase 1: encode + metrics =================
    {
        const float4* aR = (const float4*)(ampR + b*2048);
        const float4* aI = (const float4*)(ampI + b*2048);
#pragma unroll
        for (int i = 0; i < 2; i++) {
            int c = t + i*256;
            *(float4*)&br[c*4] = aR[c];
            *(float4*)&bi[c*4] = aI[c];
        }
    }
    Urs[t] = Ur[t]; Uis[t] = Ui[t];
    if (t < 16) {
        float p = phases[b*16 + t];
        phl[t] = p; csn[t] = cosf(p); snn[t] = sinf(p);
    }
    __syncthreads();
    // rotate by phase
#pragma unroll
    for (int i = 0; i < 8; i++) {
        int idx = t + i*256;
        int n2 = idx >> 7;
        float ar = br[idx], ai = bi[idx];
        float cc = csn[n2], ss = snn[n2];
        br[idx] = ar*cc - ai*ss;
        bi[idx] = ar*ss + ai*cc;
    }
    __syncthreads();
    // per-n norms of state
    {
        const int n2 = t >> 4, g = t & 15;
        const float* pr  = &br[n2*128 + g*8];
        const float* pi2 = &bi[n2*128 + g*8];
        float s = 0.0f;
#pragma unroll
        for (int j = 0; j < 8; j++) s += pr[j]*pr[j] + pi2[j]*pi2[j];
        red[t] = s;
    }
    __syncthreads();
    if (t < 16) {
        float s = 0.0f;
#pragma unroll
        for (int g2 = 0; g2 < 16; g2++) s += red[t*16 + g2];
        invn[t] = 1.0f / sqrtf(s + 1e-8f);
    }
    __syncthreads();
#pragma unroll
    for (int i = 0; i < 8; i++) {
        int idx = t + i*256;
        float iv = invn[idx >> 7];
        br[idx] *= iv; bi[idx] *= iv;
    }
    __syncthreads();
    // interference: ir/ii[n][d] = sum_m state[m,d] * U[m,n]  (complex)
#pragma unroll
    for (int rep = 0; rep < 8; rep++) {
        int o = t + rep*256;
        int n2 = o >> 7, d = o & 127;
        float ar = 0.0f, ai = 0.0f;
#pragma unroll
        for (int m = 0; m < 16; m++) {
            float vr = br[m*128 + d], vi = bi[m*128 + d];
            float ur = Urs[m*16 + n2], ui = Uis[m*16 + n2];
            ar += vr*ur - vi*ui;
            ai += vr*ui + vi*ur;
        }
        ir[n2*132 + d] = ar; ii[n2*132 + d] = ai;
    }
    __syncthreads();
    // purity / frobenius per n
    {
        const int n2 = t >> 4, g = t & 15;
        float s2 = 0.0f, s4 = 0.0f;
#pragma unroll
        for (int j = 0; j < 8; j++) {
            float xr = ir[n2*132 + g*8+j], xi = ii[n2*132 + g*8+j];
            float m2 = xr*xr + xi*xi;
            s2 += m2; s4 += m2*m2;
        }
        red[t] = s2; red2[t] = s4;
    }
    __syncthreads();
    if (t < 16) {
        float S2 = 0.0f, S4 = 0.0f;
#pragma unroll
        for (int g2 = 0; g2 < 16; g2++) { S2 += red[t*16+g2]; S4 += red2[t*16+g2]; }
        purs[t] = S4 / (S2*S2 + 1e-8f);
        fnv[t] = sqrtf(S2 + 1e-8f);
    }
    __syncthreads();
    if (t == 0) {
        float pb = 0.0f;
#pragma unroll
        for (int n2 = 0; n2 < 16; n2++) pb += purs[n2];
        pb *= (1.0f/16.0f);
        atomicAdd(pur_out, pb * INV_B);
        atomicAdd(ent_out, -logf(pb + 1e-8f) * INV_B);
    }
    if (t == 1) {
        float mean = 0.0f;
#pragma unroll
        for (int n2 = 0; n2 < 16; n2++) mean += phl[n2];
        mean *= (1.0f/16.0f);
        float var = 0.0f;
#pragma unroll
        for (int n2 = 0; n2 < 16; n2++) { float dv = phl[n2] - mean; var += dv*dv; }
        var *= (1.0f/15.0f);
        atomicAdd(pv_out, var * INV_B);
    }
    // fidelity (one (i,j) pair per thread) — reads ir/ii/fnv only
    {
        const int i2 = t >> 4, j2 = t & 15;
        float Rt = 0.0f, It = 0.0f;
#pragma unroll
        for (int d0 = 0; d0 < 128; d0 += 4) {
            float4 xr = *(const float4*)&ir[i2*132 + d0];
            float4 xi = *(const float4*)&ii[i2*132 + d0];
            float4 yr = *(const float4*)&ir[j2*132 + d0];
            float4 yi = *(const float4*)&ii[j2*132 + d0];
            Rt += xr.x*yr.x + xi.x*yi.x;  It += xr.x*yi.x - xi.x*yr.x;
            Rt += xr.y*yr.y + xi.y*yi.y;  It += xr.y*yi.y - xi.y*yr.y;
            Rt += xr.z*yr.z + xi.z*yi.z;  It += xr.z*yi.z - xi.z*yr.z;
            Rt += xr.w*yr.w + xi.w*yi.w;  It += xr.w*yi.w - xi.w*yr.w;
        }
        float inv = 1.0f / (fnv[i2]*fnv[j2]);
        float F = (Rt*Rt + It*It) * inv * inv;
        F = fminf(fmaxf(F, 0.0f), 1.0f);
        fid[b*256 + t] = F;
    }

    // ================= phase 2: qkv projections (real GEMMs) =================
    // qkv_r[n,c] = sum_d ir[n,d]*Wqkv_r[d,c] + bqkv_r[c]; qkv_i from ii/W_i.
    // W chunk = 4 d-rows (1536 fl each array), staged at br/bi region (dead).
    const int cg = t >> 4, nn = t & 15;
    float aq[24], bq[24];
#pragma unroll
    for (int j = 0; j < 24; j++) { aq[j] = 0.0f; bq[j] = 0.0f; }
    for (int d0 = 0; d0 < 128; d0 += 4) {
        __syncthreads();   // prior chunk reads done (first iter: fid reads done)
#pragma unroll
        for (int i = 0; i < 6; i++) {
            int idx = t + i*256;
            Wrc[idx] = Wqkv_r[d0*384 + idx];
            Wic[idx] = Wqkv_i[d0*384 + idx];
        }
        __syncthreads();
#pragma unroll
        for (int dd = 0; dd < 4; dd++) {
            const float arr = ir[nn*132 + d0 + dd];
            const float aii = ii[nn*132 + d0 + dd];
#pragma unroll
            for (int s2 = 0; s2 < 6; s2++) {
                const float4 wr4 = *(const float4*)&Wrc[dd*384 + cg*4 + 64*s2];
                const float4 wi4 = *(const float4*)&Wic[dd*384 + cg*4 + 64*s2];
                aq[s2*4+0] = fmaf(arr, wr4.x, aq[s2*4+0]);
                aq[s2*4+1] = fmaf(arr, wr4.y, aq[s2*4+1]);
                aq[s2*4+2] = fmaf(arr, wr4.z, aq[s2*4+2]);
                aq[s2*4+3] = fmaf(arr, wr4.w, aq[s2*4+3]);
                bq[s2*4+0] = fmaf(aii, wi4.x, bq[s2*4+0]);
                bq[s2*4+1] = fmaf(aii, wi4.y, bq[s2*4+1]);
                bq[s2*4+2] = fmaf(aii, wi4.z, bq[s2*4+2]);
                bq[s2*4+3] = fmaf(aii, wi4.w, bq[s2*4+3]);
            }
        }
    }
    __syncthreads();   // all ir/ii + W reads complete; overlay q/k/v over 0..12480
#pragma unroll
    for (int s2 = 0; s2 < 6; s2++) {
#pragma unroll
        for (int j = 0; j < 4; j++) {
            const int c = cg*4 + 64*s2 + j;
            float qvr = aq[s2*4+j] + bqkv_r[c];
            float qvi = bq[s2*4+j] + bqkv_i[c];
            if (s2 < 2)      { qr2[nn*130 + c]         = qvr; qi2[nn*130 + c]         = qvi; }
            else if (s2 < 4) { kr2[nn*130 + (c-128)]   = qvr; ki2[nn*130 + (c-128)]   = qvi; }
            else             { vr2[nn*130 + (c-256)]   = qvr; vi2[nn*130 + (c-256)]   = qvi; }
        }
    }
    __syncthreads();

    // ================= phase 3: scores + magnitude softmax =================
    {
        const int nq = t >> 4, m = t & 15;
#pragma unroll
        for (int h = 0; h < 4; h++) {
            float ar = 0.0f, ai = 0.0f;
            const int bqo = h*32;
#pragma unroll
            for (int d0 = 0; d0 < 32; d0 += 4) {
                float4 q_r = *(const float4*)&qr2[nq*130 + bqo + d0];
                float4 k_r = *(const float4*)&kr2[m*130  + bqo + d0];
                float4 q_i = *(const float4*)&qi2[nq*130 + bqo + d0];
                float4 k_i = *(const float4*)&ki2[m*130  + bqo + d0];
                ar += q_r.x*k_r.x + q_i.x*k_i.x + q_r.y*k_r.y + q_i.y*k_i.y
                    + q_r.z*k_r.z + q_i.z*k_i.z + q_r.w*k_r.w + q_i.w*k_i.w;
                ai += q_i.x*k_r.x - q_r.x*k_i.x + q_i.y*k_r.y - q_r.y*k_i.y
                    + q_i.z*k_r.z - q_r.z*k_i.z + q_i.w*k_r.w - q_r.w*k_i.w;
            }
            wbuf[h*272 + nq*17 + m] = sqrtf(ar*ar + ai*ai) * SCALE_F;
        }
    }
    __syncthreads();
    if (t < 64) {
        const int h = t >> 4, n2 = t & 15;
        float* row = &wbuf[h*272 + n2*17];
        float mx = row[0];
#pragma unroll
        for (int k = 1; k < 16; k++) mx = fmaxf(mx, row[k]);
        float ev[16];
        float sum = 0.0f;
#pragma unroll
        for (int k = 0; k < 16; k++) { ev[k] = expf(row[k] - mx); sum += ev[k]; }
        float inv = 1.0f / sum;
#pragma unroll
        for (int k = 0; k < 16; k++) row[k] = ev[k] * inv;
    }
    __syncthreads();

    // ================= phase 4a: per-head PV -> o in LDS =================
    {
        const int og = t >> 4, n2 = t & 15;
        const int hh = og >> 2;
        float por[8] = {0,0,0,0,0,0,0,0}, poi[8] = {0,0,0,0,0,0,0,0};
#pragma unroll
        for (int m2 = 0; m2 < 16; m2++) {
            float w = wbuf[hh*272 + n2*17 + m2];
            float4 v0 = *(const float4*)&vr2[m2*130 + og*8];
            float4 v1 = *(const float4*)&vr2[m2*130 + og*8 + 4];
            float4 u0 = *(const float4*)&vi2[m2*130 + og*8];
            float4 u1 = *(const float4*)&vi2[m2*130 + og*8 + 4];
            por[0] = fmaf(w, v0.x, por[0]); por[1] = fmaf(w, v0.y, por[1]);
            por[2] = fmaf(w, v0.z, por[2]); por[3] = fmaf(w, v0.w, por[3]);
            por[4] = fmaf(w, v1.x, por[4]); por[5] = fmaf(w, v1.y, por[5]);
            por[6] = fmaf(w, v1.z, por[6]); por[7] = fmaf(w, v1.w, por[7]);
            poi[0] = fmaf(w, u0.x, poi[0]); poi[1] = fmaf(w, u0.y, poi[1]);
            poi[2] = fmaf(w, u0.z, poi[2]); poi[3] = fmaf(w, u0.w, poi[3]);
            poi[4] = fmaf(w, u1.x, poi[4]); poi[5] = fmaf(w, u1.y, poi[5]);
            poi[6] = fmaf(w, u1.z, poi[6]); poi[7] = fmaf(w, u1.w, poi[7]);
        }
        __syncthreads();   // q reads long done; make or_ overlay safe vs phase 3
#pragma unroll
        for (int j = 0; j < 8; j++) {
            or_[n2*130 + og*8 + j] = por[j];
            oi_[n2*130 + og*8 + j] = poi[j];
        }
    }

    // ================= phase 4b: att = o @ Wout + bias =================
    {
        const int og = t >> 4, n2 = t & 15;
        float atr[8] = {0,0,0,0,0,0,0,0}, ati[8] = {0,0,0,0,0,0,0,0};
        for (int d0 = 0; d0 < 128; d0 += 8) {
            __syncthreads();   // prior chunk reads done (first iter: or_ writes done)
            *(float4*)&Wor[t*4] = *(const float4*)&Wout_r[d0*128 + t*4];
            *(float4*)&Woi[t*4] = *(const float4*)&Wout_i[d0*128 + t*4];
            __syncthreads();
#pragma unroll
            for (int dd = 0; dd < 8; dd++) {
                const float a_r = or_[n2*130 + d0 + dd];
                const float a_i = oi_[n2*130 + d0 + dd];
                float4 w0 = *(const float4*)&Wor[dd*128 + og*8];
                float4 w1 = *(const float4*)&Wor[dd*128 + og*8 + 4];
                float4 u0 = *(const float4*)&Woi[dd*128 + og*8];
                float4 u1 = *(const float4*)&Woi[dd*128 + og*8 + 4];
                atr[0] = fmaf(a_r, w0.x, atr[0]); atr[1] = fmaf(a_r, w0.y, atr[1]);
                atr[2] = fmaf(a_r, w0.z, atr[2]); atr[3] = fmaf(a_r, w0.w, atr[3]);
                atr[4] = fmaf(a_r, w1.x, atr[4]); atr[5] = fmaf(a_r, w1.y, atr[5]);
                atr[6] = fmaf(a_r, w1.z, atr[6]); atr[7] = fmaf(a_r, w1.w, atr[7]);
                ati[0] = fmaf(a_i, u0.x, ati[0]); ati[1] = fmaf(a_i, u0.y, ati[1]);
                ati[2] = fmaf(a_i, u0.z, ati[2]); ati[3] = fmaf(a_i, u0.w, ati[3]);
                ati[4] = fmaf(a_i, u1.x, ati[4]); ati[5] = fmaf(a_i, u1.y, ati[5]);
                ati[6] = fmaf(a_i, u1.z, ati[6]); ati[7] = fmaf(a_i, u1.w, ati[7]);
            }
        }
        const float4 br0 = *(const float4*)&bout_r[og*8];
        const float4 br1 = *(const float4*)&bout_r[og*8 + 4];
        const float4 bi0 = *(const float4*)&bout_i[og*8];
        const float4 bi1 = *(const float4*)&bout_i[og*8 + 4];
        float4 o0 = make_float4(atr[0]+br0.x, atr[1]+br0.y, atr[2]+br0.z, atr[3]+br0.w);
        float4 o1 = make_float4(atr[4]+br1.x, atr[5]+br1.y, atr[6]+br1.z, atr[7]+br1.w);
        float4 e0 = make_float4(ati[0]+bi0.x, ati[1]+bi0.y, ati[2]+bi0.z, ati[3]+bi0.w);
        float4 e1 = make_float4(ati[4]+bi1.x, ati[5]+bi1.y, ati[6]+bi1.z, ati[7]+bi1.w);
        size_t gbase = b*2048 + (size_t)n2*128 + og*8;
        *(float4*)&attR[gbase]     = o0;
        *(float4*)&attR[gbase + 4] = o1;
        *(float4*)&attI[gbase]     = e0;
        *(float4*)&attI[gbase + 4] = e1;
        // stash for means (over dead v region)
        *(float4*)&attSr[n2*130 + og*8]     = o0;
        *(float4*)&attSr[n2*130 + og*8 + 4] = o1;
        *(float4*)&attSi[n2*130 + og*8]     = e0;
        *(float4*)&attSi[n2*130 + og*8 + 4] = e1;
    }
    __syncthreads();

    // ================= phase 5: means over n =================
    if (t < 128) {
        const int d = t;
        float s = 0.0f;
#pragma unroll
        for (int n2 = 0; n2 < 16; n2++) s += attSr[n2*130 + d];
        attmR[b*128 + d] = s * (1.0f/16.0f);
    } else {
        const int d = t - 128;
        float s = 0.0f;
#pragma unroll
        for (int n2 = 0; n2 < 16; n2++) s += attSi[n2*130 + d];
        attmI[b*128 + d] = s * (1.0f/16.0f);
    }
}

// =====================================================================
// mag: grid (B/32, 16). Each block: 32 b-rows, one n. mag[b,n] only.
// =====================================================================
__global__ __launch_bounds__(256) void mag_kernel(const float* __restrict__ attR,
                                                  const float* __restrict__ attI,
                                                  const float* __restrict__ M_r,
                                                  const float* __restrict__ M_i,
                                                  float* __restrict__ mag) {
    __shared__ float ar_s[32*128];
    __shared__ float ai_s[32*128];
    const int t = threadIdx.x;
    const size_t b0 = (size_t)blockIdx.x * 32;
    const int n = blockIdx.y;
#pragma unroll
    for (int i = 0; i < 4; i++) {
        int c = t + i*256;
        int row = c >> 5, d4 = (c & 31) << 2;
        *(float4*)&ar_s[row*128 + d4] = *(const float4*)&attR[((b0+row)*16 + n)*128 + d4];
        *(float4*)&ai_s[row*128 + d4] = *(const float4*)&attI[((b0+row)*16 + n)*128 + d4];
    }
    __syncthreads();
    const int ol = t & 63;
    const int rg = t >> 6;
    const int obase = ol * 4;
    float mr[8][4], mi[8][4];
#pragma unroll
    for (int i = 0; i < 8; i++)
#pragma unroll
        for (int j = 0; j < 4; j++) { mr[i][j] = 0.0f; mi[i][j] = 0.0f; }
    const float* Mrp = M_r + (size_t)n*DD*OO;
    const float* Mip = M_i + (size_t)n*DD*OO;
    for (int k0 = 0; k0 < 128; k0 += 4) {
        float4 Mr4[4], Mi4[4];
#pragma unroll
        for (int u = 0; u < 4; u++) {
            Mr4[u] = *(const float4*)&Mrp[(k0+u)*256 + obase];
            Mi4[u] = *(const float4*)&Mip[(k0+u)*256 + obase];
        }
#pragma unroll
        for (int r8 = 0; r8 < 8; r8++) {
            const int row = rg*8 + r8;
            float4 a4 = *(const float4*)&ar_s[row*128 + k0];
            float4 c4 = *(const float4*)&ai_s[row*128 + k0];
            float arv[4] = {a4.x, a4.y, a4.z, a4.w};
            float aiv[4] = {c4.x, c4.y, c4.z, c4.w};
#pragma unroll
            for (int u = 0; u < 4; u++) {
                float ar = arv[u], ai = aiv[u];
                mr[r8][0] = fmaf(ar, Mr4[u].x, mr[r8][0]); mr[r8][0] = fmaf(-ai, Mi4[u].x, mr[r8][0]);
                mr[r8][1] = fmaf(ar, Mr4[u].y, mr[r8][1]); mr[r8][1] = fmaf(-ai, Mi4[u].y, mr[r8][1]);
                mr[r8][2] = fmaf(ar, Mr4[u].z, mr[r8][2]); mr[r8][2] = fmaf(-ai, Mi4[u].z, mr[r8][2]);
                mr[r8][3] = fmaf(ar, Mr4[u].w, mr[r8][3]); mr[r8][3] = fmaf(-ai, Mi4[u].w, mr[r8][3]);
                mi[r8][0] = fmaf(ar, Mi4[u].x, mi[r8][0]); mi[r8][0] = fmaf( ai, Mr4[u].x, mi[r8][0]);
                mi[r8][1] = fmaf(ar, Mi4[u].y, mi[r8][1]); mi[r8][1] = fmaf( ai, Mr4[u].y, mi[r8][1]);
                mi[r8][2] = fmaf(ar, Mi4[u].z, mi[r8][2]); mi[r8][2] = fmaf( ai, Mr4[u].z, mi[r8][2]);
                mi[r8][3] = fmaf(ar, Mi4[u].w, mi[r8][3]); mi[r8][3] = fmaf( ai, Mr4[u].w, mi[r8][3]);
            }
        }
    }
#pragma unroll
    for (int r8 = 0; r8 < 8; r8++) {
        const int row = rg*8 + r8;
        float p = 0.0f;
#pragma unroll
        for (int u = 0; u < 4; u++)
            p += sqrtf(mr[r8][u]*mr[r8][u] + mi[r8][u]*mi[r8][u]);
#pragma unroll
        for (int s = 32; s > 0; s >>= 1) p += __shfl_down(p, s, 64);
        if (ol == 0) mag[(b0+row)*16 + n] = p * (1.0f/256.0f);
    }
}

// =====================================================================
// probs: softmax over n of mag
// =====================================================================
__global__ __launch_bounds__(256) void probs_kernel(const float* __restrict__ mag,
                                                    float* __restrict__ probs) {
    const int b = blockIdx.x*256 + threadIdx.x;   // grid 32 -> 8192 threads
    float v[16];
    float mx = -1e30f;
#pragma unroll
    for (int n2 = 0; n2 < 16; n2++) { v[n2] = mag[b*16 + n2]; mx = fmaxf(mx, v[n2]); }
    float sum = 0.0f;
#pragma unroll
    for (int n2 = 0; n2 < 16; n2++) { v[n2] = expf(v[n2] - mx); sum += v[n2]; }
    float inv = 1.0f / sum;
#pragma unroll
    for (int n2 = 0; n2 < 16; n2++) probs[b*16 + n2] = v[n2] * inv;
}

// =====================================================================
// wclass: fused weighted measurement -> classical. NO atomics.
// grid = B/16 = 512 blocks, 512 threads. Block: 16 b-rows x 256 o, loops n.
// thread = (ol 0..63 -> o quad, rg 0..7 -> rows rg*2+{0,1})
// =====================================================================
__global__ __launch_bounds__(512, 4) void wclass_kernel(const float* __restrict__ attR,
                                                        const float* __restrict__ attI,
                                                        const float* __restrict__ M_r,
                                                        const float* __restrict__ M_i,
                                                        const float* __restrict__ probs,
                                                        float* __restrict__ cls) {
    __shared__ float ar_s[16*128];
    __shared__ float ai_s[16*128];
    __shared__ float p_s[256];
    const int t = threadIdx.x;
    const size_t b0 = (size_t)blockIdx.x * 16;
    const int ol = t & 63;
    const int rg = t >> 6;
    const int obase = ol * 4;
    float aor[2][4], aoi[2][4];
#pragma unroll
    for (int r2 = 0; r2 < 2; r2++)
#pragma unroll
        for (int u = 0; u < 4; u++) { aor[r2][u] = 0.0f; aoi[r2][u] = 0.0f; }
    if (t < 256) p_s[t] = probs[b0*16 + t];

    for (int n = 0; n < 16; n++) {
        __syncthreads();   // previous tile fully consumed (and p_s ready on iter 0)
        {
            int row = t >> 5, d4 = (t & 31) << 2;
            *(float4*)&ar_s[row*128 + d4] = *(const float4*)&attR[((b0+row)*16 + n)*128 + d4];
            *(float4*)&ai_s[row*128 + d4] = *(const float4*)&attI[((b0+row)*16 + n)*128 + d4];
        }
        __syncthreads();
        float mr[2][4], mi[2][4];
#pragma unroll
        for (int r2 = 0; r2 < 2; r2++)
#pragma unroll
            for (int u = 0; u < 4; u++) { mr[r2][u] = 0.0f; mi[r2][u] = 0.0f; }
        const float* Mrp = M_r + (size_t)n*DD*OO;
        const float* Mip = M_i + (size_t)n*DD*OO;
        for (int k0 = 0; k0 < 128; k0 += 4) {
            float4 Mr4[4], Mi4[4];
#pragma unroll
            for (int u = 0; u < 4; u++) {
                Mr4[u] = *(const float4*)&Mrp[(k0+u)*256 + obase];
                Mi4[u] = *(const float4*)&Mip[(k0+u)*256 + obase];
            }
#pragma unroll
            for (int r2 = 0; r2 < 2; r2++) {
                const int row = rg*2 + r2;
                float4 a4 = *(const float4*)&ar_s[row*128 + k0];
                float4 c4 = *(const float4*)&ai_s[row*128 + k0];
                float arv[4] = {a4.x, a4.y, a4.z, a4.w};
                float aiv[4] = {c4.x, c4.y, c4.z, c4.w};
#pragma unroll
                for (int u = 0; u < 4; u++) {
                    float ar = arv[u], ai = aiv[u];
                    mr[r2][0] = fmaf(ar, Mr4[u].x, mr[r2][0]); mr[r2][0] = fmaf(-ai, Mi4[u].x, mr[r2][0]);
                    mr[r2][1] = fmaf(ar, Mr4[u].y, mr[r2][1]); mr[r2][1] = fmaf(-ai, Mi4[u].y, mr[r2][1]);
                    mr[r2][2] = fmaf(ar, Mr4[u].z, mr[r2][2]); mr[r2][2] = fmaf(-ai, Mi4[u].z, mr[r2][2]);
                    mr[r2][3] = fmaf(ar, Mr4[u].w, mr[r2][3]); mr[r2][3] = fmaf(-ai, Mi4[u].w, mr[r2][3]);
                    mi[r2][0] = fmaf(ar, Mi4[u].x, mi[r2][0]); mi[r2][0] = fmaf( ai, Mr4[u].x, mi[r2][0]);
                    mi[r2][1] = fmaf(ar, Mi4[u].y, mi[r2][1]); mi[r2][1] = fmaf( ai, Mr4[u].y, mi[r2][1]);
                    mi[r2][2] = fmaf(ar, Mi4[u].z, mi[r2][2]); mi[r2][2] = fmaf( ai, Mr4[u].z, mi[r2][2]);
                    mi[r2][3] = fmaf(ar, Mi4[u].w, mi[r2][3]); mi[r2][3] = fmaf( ai, Mr4[u].w, mi[r2][3]);
                }
            }
        }
#pragma unroll
        for (int r2 = 0; r2 < 2; r2++) {
            float p = p_s[(rg*2 + r2)*16 + n];
#pragma unroll
            for (int u = 0; u < 4; u++) {
                aor[r2][u] = fmaf(p, mr[r2][u], aor[r2][u]);
                aoi[r2][u] = fmaf(p, mi[r2][u], aoi[r2][u]);
            }
        }
    }
#pragma unroll
    for (int r2 = 0; r2 < 2; r2++) {
        const int row = rg*2 + r2;
        float4 o;
        o.x = sqrtf(aor[r2][0]*aor[r2][0] + aoi[r2][0]*aoi[r2][0]);
        o.y = sqrtf(aor[r2][1]*aor[r2][1] + aoi[r2][1]*aoi[r2][1]);
        o.z = sqrtf(aor[r2][2]*aor[r2][2] + aoi[r2][2]*aoi[r2][2]);
        o.w = sqrtf(aor[r2][3]*aor[r2][3] + aoi[r2][3]*aoi[r2][3]);
        *(float4*)&cls[(b0+row)*256 + obase] = o;
    }
}

// =====================================================================
// host launcher
// =====================================================================
extern "C" void kernel_launch(void* const* d_in, const int* in_sizes, int n_in,
                              void* d_out, int out_size, void* d_ws, size_t ws_size,
                              hipStream_t stream) {
    const float* x        = (const float*)d_in[0];
    const float* W_amp_r  = (const float*)d_in[1];
    const float* b_amp_r  = (const float*)d_in[2];
    const float* W_amp_i  = (const float*)d_in[3];
    const float* b_amp_i  = (const float*)d_in[4];
    const float* W_ph     = (const float*)d_in[5];
    const float* b_ph     = (const float*)d_in[6];
    const float* A_param  = (const float*)d_in[7];
    const float* Wqkv_r   = (const float*)d_in[8];
    const float* bqkv_r   = (const float*)d_in[9];
    const float* Wqkv_i   = (const float*)d_in[10];
    const float* bqkv_i   = (const float*)d_in[11];
    const float* Wout_r   = (const float*)d_in[12];
    const float* bout_r   = (const float*)d_in[13];
    const float* Wout_i   = (const float*)d_in[14];
    const float* bout_i   = (const float*)d_in[15];
    const float* M_r      = (const float*)d_in[16];
    const float* M_i      = (const float*)d_in[17];
    float* out = (float*)d_out;
    float* ws  = (float*)d_ws;

    // ws layout (floats): amp region reused in-place as att. Total ~135 MB.
    float* ampR   = ws;                     // 16777216
    float* ampI   = ws + 16777216;          // 16777216
    float* attR   = ampR;
    float* attI   = ampI;
    float* phases = ws + 33554432;          // 131072
    float* mag    = ws + 33685504;          // 131072
    float* UrP    = ws + 33816576;          // 256
    float* UiP    = ws + 33816832;          // 256

    // zero the atomic-accumulated scalar outputs
    hipMemsetAsync(out + OFF_PUR, 0, 2*sizeof(float), stream);
    hipMemsetAsync(out + OFF_PV,  0, sizeof(float), stream);

    cayley_kernel<<<1, 256, 0, stream>>>(A_param, UrP, UiP);

    gemm_f32<<<dim3(64, 16), 256, 0, stream>>>(x, 512, W_amp_r, 2048, b_amp_r, ampR, 2048, 512);
    gemm_f32<<<dim3(64, 16), 256, 0, stream>>>(x, 512, W_amp_i, 2048, b_amp_i, ampI, 2048, 512);
    phases_kernel<<<8192, 256, 0, stream>>>(x, W_ph, b_ph, phases);

    mega_kernel<<<8192, 256, 0, stream>>>(ampR, ampI, phases, UrP, UiP,
                                          Wqkv_r, bqkv_r, Wqkv_i, bqkv_i,
                                          Wout_r, bout_r, Wout_i, bout_i,
                                          attR, attI,
                                          out + OFF_FID, out + OFF_ATTRM, out + OFF_ATTIM,
                                          out + OFF_PUR, out + OFF_ENT, out + OFF_PV);

    mag_kernel<<<dim3(256, 16), 256, 0, stream>>>(attR, attI, M_r, M_i, mag);
    probs_kernel<<<32, 256, 0, stream>>>(mag, out + OFF_PROBS);
    wclass_kernel<<<512, 512, 0, stream>>>(attR, attI, M_r, M_i, out + OFF_PROBS, out + OFF_CLASS);
}